// Round 1
// 1271.472 us; speedup vs baseline: 1.0242x; 1.0242x over previous
//
#include <hip/hip_runtime.h>
#include <hip/hip_bf16.h>
#include <stdint.h>

// B=4, S=4096, D=2048. M = B*S = 16384 token rows.
// VERIFIED: inputs fp32 dict-order, OUTPUT FP32, MFMA layouts correct (R7 pass,
// absmax 0.03125). Prev round: 1302 us; k_gemm_if 575 us with
// SQ_LDS_BANK_CONFLICT=2.5e7 (4-way conflict on ds_read_b128 of [128][32]
// row-major tiles). This round: both-sides XOR swizzle (slot ^= (row>>1)&3)
// on staging global-source + LDS read (LDS dest stays linear for
// global_load_lds per rule #21). Expect conflicts -> ~0, total ~1000 us.
#define M_DIM 16384
#define N_DIM 2048
#define K_DIM 2048
#define S_LEN 4096
#define NCHUNK 64
#define CLEN 64
#define EPSV 1e-5f

typedef __hip_bfloat16 bf16;
typedef __attribute__((ext_vector_type(8))) short bf16x8;
typedef __attribute__((ext_vector_type(4))) float floatx4;

__device__ inline short f2b(float v) {
  __hip_bfloat16 h = __float2bfloat16(v);
  return *(short*)&h;
}
__device__ inline float sigm(float v) { return 1.f / (1.f + __expf(-v)); }

// ---- async global->LDS, 16B/lane. LDS dest = wave-uniform base + lane*16. ----
__device__ inline void async_ld16(const bf16* g, bf16* l) {
  __builtin_amdgcn_global_load_lds(
      (__attribute__((address_space(1))) void*)(void*)g,
      (__attribute__((address_space(3))) void*)(void*)l, 16, 0, 0);
}

// Stage 128x32 bf16 tile from row-major global (ld elems) into LDS [128][32],
// XOR-swizzled: physical 16B slot s at row r holds global slot s ^ ((r>>1)&3).
// LDS dest is linear (gload_lds requirement); the swizzle is applied by
// permuting the per-lane GLOBAL source slot (same 64B segment -> still
// coalesced). Wave w covers rows [w*32, w*32+32) as 2 instrs of 16 rows.
__device__ inline void stage128x32(const bf16* gtile, bf16* sbuf, size_t ld, int lane, int w) {
#pragma unroll
  for (int j = 0; j < 2; ++j) {
    const int rseg = w * 32 + j * 16;
    const int row = rseg + (lane >> 2);
    const int slot = (lane & 3) ^ ((row >> 1) & 3);
    const bf16* g = gtile + (size_t)row * ld + (size_t)slot * 8;
    async_ld16(g, sbuf + rseg * 32);
  }
}

// Read logical slot ko/8 of row: physical slot = (ko/8) ^ ((row>>1)&3).
// Bank math: consecutive 8 lanes of the wave's ds_read_b128 now cover all
// 8 (parity x slot) positions = all 32 banks -> conflict-free.
__device__ inline bf16x8 fragld(const bf16* sbuf, int row, int ko) {
  return *(const bf16x8*)(sbuf + row * 32 + (ko ^ (((row >> 1) & 3) << 3)));
}

// ---------------- conversions ----------------
__global__ __launch_bounds__(256) void k_cvt_x(const float* __restrict__ X, bf16* __restrict__ Xb) {
  size_t i = ((size_t)blockIdx.x * 256 + threadIdx.x) * 8;
  const float4 lo = *(const float4*)(X + i);
  const float4 hi = *(const float4*)(X + i + 4);
  bf16x8 v;
  v[0] = f2b(lo.x); v[1] = f2b(lo.y); v[2] = f2b(lo.z); v[3] = f2b(lo.w);
  v[4] = f2b(hi.x); v[5] = f2b(hi.y); v[6] = f2b(hi.z); v[7] = f2b(hi.w);
  *(bf16x8*)(Xb + i) = v;
}

// Wi -> W1b, Wf -> W2b
__global__ __launch_bounds__(256) void k_cvt_wif(const float* __restrict__ Wi, const float* __restrict__ Wf,
                                                 bf16* __restrict__ W1b, bf16* __restrict__ W2b) {
  size_t i = ((size_t)blockIdx.x * 256 + threadIdx.x) * 8;
  {
    const float4 lo = *(const float4*)(Wi + i);
    const float4 hi = *(const float4*)(Wi + i + 4);
    bf16x8 v;
    v[0] = f2b(lo.x); v[1] = f2b(lo.y); v[2] = f2b(lo.z); v[3] = f2b(lo.w);
    v[4] = f2b(hi.x); v[5] = f2b(hi.y); v[6] = f2b(hi.z); v[7] = f2b(hi.w);
    *(bf16x8*)(W1b + i) = v;
  }
  {
    const float4 lo = *(const float4*)(Wf + i);
    const float4 hi = *(const float4*)(Wf + i + 4);
    bf16x8 v;
    v[0] = f2b(lo.x); v[1] = f2b(lo.y); v[2] = f2b(lo.z); v[3] = f2b(lo.w);
    v[4] = f2b(hi.x); v[5] = f2b(hi.y); v[6] = f2b(hi.z); v[7] = f2b(hi.w);
    *(bf16x8*)(W2b + i) = v;
  }
}

// Wg -> W1b (reuse), Wo*w_norm -> W2b (reuse). Runs after k_gemm_if (stream order).
__global__ __launch_bounds__(256) void k_cvt_g_wos(const float* __restrict__ Wg, const float* __restrict__ Wo,
                                                   const float* __restrict__ wn,
                                                   bf16* __restrict__ W1b, bf16* __restrict__ W2b) {
  size_t i = ((size_t)blockIdx.x * 256 + threadIdx.x) * 8;
  {
    const float4 lo = *(const float4*)(Wg + i);
    const float4 hi = *(const float4*)(Wg + i + 4);
    bf16x8 v;
    v[0] = f2b(lo.x); v[1] = f2b(lo.y); v[2] = f2b(lo.z); v[3] = f2b(lo.w);
    v[4] = f2b(hi.x); v[5] = f2b(hi.y); v[6] = f2b(hi.z); v[7] = f2b(hi.w);
    *(bf16x8*)(W1b + i) = v;
  }
  {
    const float4 lo = *(const float4*)(Wo + i);
    const float4 hi = *(const float4*)(Wo + i + 4);
    const int e = (int)(i & (N_DIM - 1));
    bf16x8 v;
    v[0] = f2b(lo.x * wn[e + 0]); v[1] = f2b(lo.y * wn[e + 1]);
    v[2] = f2b(lo.z * wn[e + 2]); v[3] = f2b(lo.w * wn[e + 3]);
    v[4] = f2b(hi.x * wn[e + 4]); v[5] = f2b(hi.y * wn[e + 5]);
    v[6] = f2b(hi.z * wn[e + 6]); v[7] = f2b(hi.w * wn[e + 7]);
    *(bf16x8*)(W2b + i) = v;
  }
}

// ---------------- GEMM 1: i,f fused (async staging) -> raw bf16 ----------------
__global__ __launch_bounds__(256) void k_gemm_if(
    const bf16* __restrict__ Xb, const bf16* __restrict__ Wib, const bf16* __restrict__ Wfb,
    bf16* __restrict__ Ib, bf16* __restrict__ Fb) {
  __shared__ __align__(16) bf16 sA[128 * 32];
  __shared__ __align__(16) bf16 sI[128 * 32];
  __shared__ __align__(16) bf16 sF[128 * 32];
  const int tid = threadIdx.x, lane = tid & 63, w = tid >> 6;
  const int wm = w & 1, wn = w >> 1;
  const size_t bm = (size_t)blockIdx.y * 128, bn = (size_t)blockIdx.x * 128;
  const int kq = lane >> 4, kr = lane & 15;
  floatx4 ai[4][4], af[4][4];
#pragma unroll
  for (int p = 0; p < 4; ++p)
#pragma unroll
    for (int q = 0; q < 4; ++q) {
      ai[p][q] = floatx4{0.f, 0.f, 0.f, 0.f};
      af[p][q] = floatx4{0.f, 0.f, 0.f, 0.f};
    }
  for (int k0 = 0; k0 < K_DIM; k0 += 32) {
    stage128x32(Xb + bm * K_DIM + k0, sA, K_DIM, lane, w);
    stage128x32(Wib + bn * K_DIM + k0, sI, K_DIM, lane, w);
    stage128x32(Wfb + bn * K_DIM + k0, sF, K_DIM, lane, w);
    __syncthreads();
    bf16x8 fa[4], fi[4], ff[4];
#pragma unroll
    for (int t = 0; t < 4; ++t) {
      fa[t] = fragld(sA, wm * 64 + t * 16 + kr, kq * 8);
      fi[t] = fragld(sI, wn * 64 + t * 16 + kr, kq * 8);
      ff[t] = fragld(sF, wn * 64 + t * 16 + kr, kq * 8);
    }
#pragma unroll
    for (int p = 0; p < 4; ++p)
#pragma unroll
      for (int q = 0; q < 4; ++q) {
        ai[p][q] = __builtin_amdgcn_mfma_f32_16x16x32_bf16(fa[p], fi[q], ai[p][q], 0, 0, 0);
        af[p][q] = __builtin_amdgcn_mfma_f32_16x16x32_bf16(fa[p], ff[q], af[p][q], 0, 0, 0);
      }
    __syncthreads();
  }
#pragma unroll
  for (int p = 0; p < 4; ++p)
#pragma unroll
    for (int q = 0; q < 4; ++q)
#pragma unroll
      for (int r = 0; r < 4; ++r) {
        size_t m = bm + wm * 64 + p * 16 + kq * 4 + r;
        size_t n = bn + wn * 64 + q * 16 + kr;
        Ib[m * N_DIM + n] = __float2bfloat16(ai[p][q][r]);
        Fb[m * N_DIM + n] = __float2bfloat16(af[p][q][r]);
      }
}

// ---------------- GEMM 2: g (async) + fused gate: xg = h * silu(g) -> Fb ----------------
__global__ __launch_bounds__(256) void k_gemm_g(
    const bf16* __restrict__ Xb, const bf16* __restrict__ Wgb, const bf16* __restrict__ Hb,
    bf16* __restrict__ XGout) {
  __shared__ __align__(16) bf16 sA[128 * 32];
  __shared__ __align__(16) bf16 sB[128 * 32];
  const int tid = threadIdx.x, lane = tid & 63, w = tid >> 6;
  const int wm = w & 1, wn = w >> 1;
  const size_t bm = (size_t)blockIdx.y * 128, bn = (size_t)blockIdx.x * 128;
  const int kq = lane >> 4, kr = lane & 15;
  floatx4 ac[4][4];
#pragma unroll
  for (int p = 0; p < 4; ++p)
#pragma unroll
    for (int q = 0; q < 4; ++q) ac[p][q] = floatx4{0.f, 0.f, 0.f, 0.f};
  for (int k0 = 0; k0 < K_DIM; k0 += 32) {
    stage128x32(Xb + bm * K_DIM + k0, sA, K_DIM, lane, w);
    stage128x32(Wgb + bn * K_DIM + k0, sB, K_DIM, lane, w);
    __syncthreads();
    bf16x8 fa[4], fb[4];
#pragma unroll
    for (int t = 0; t < 4; ++t) {
      fa[t] = fragld(sA, wm * 64 + t * 16 + kr, kq * 8);
      fb[t] = fragld(sB, wn * 64 + t * 16 + kr, kq * 8);
    }
#pragma unroll
    for (int p = 0; p < 4; ++p)
#pragma unroll
      for (int q = 0; q < 4; ++q)
        ac[p][q] = __builtin_amdgcn_mfma_f32_16x16x32_bf16(fa[p], fb[q], ac[p][q], 0, 0, 0);
    __syncthreads();
  }
#pragma unroll
  for (int p = 0; p < 4; ++p)
#pragma unroll
    for (int q = 0; q < 4; ++q)
#pragma unroll
      for (int r = 0; r < 4; ++r) {
        size_t m = bm + wm * 64 + p * 16 + kq * 4 + r;
        size_t n = bn + wn * 64 + q * 16 + kr;
        float gv = ac[p][q][r];
        float hv = __bfloat162float(Hb[m * N_DIM + n]);
        XGout[m * N_DIM + n] = __float2bfloat16(hv * gv * sigm(gv));
      }
}

// ---------------- GEMM 3: out = (xg·Wo'^T) * r[m] -> FP32 (async) ----------------
__global__ __launch_bounds__(256) void k_gemm_o(
    const bf16* __restrict__ XG, const bf16* __restrict__ WoS, const float* __restrict__ rbuf,
    float* __restrict__ Out) {
  __shared__ __align__(16) bf16 sA[128 * 32];
  __shared__ __align__(16) bf16 sB[128 * 32];
  const int tid = threadIdx.x, lane = tid & 63, w = tid >> 6;
  const int wm = w & 1, wn = w >> 1;
  const size_t bm = (size_t)blockIdx.y * 128, bn = (size_t)blockIdx.x * 128;
  const int kq = lane >> 4, kr = lane & 15;
  floatx4 ac[4][4];
#pragma unroll
  for (int p = 0; p < 4; ++p)
#pragma unroll
    for (int q = 0; q < 4; ++q) ac[p][q] = floatx4{0.f, 0.f, 0.f, 0.f};
  for (int k0 = 0; k0 < K_DIM; k0 += 32) {
    stage128x32(XG + bm * K_DIM + k0, sA, K_DIM, lane, w);
    stage128x32(WoS + bn * K_DIM + k0, sB, K_DIM, lane, w);
    __syncthreads();
    bf16x8 fa[4], fb[4];
#pragma unroll
    for (int t = 0; t < 4; ++t) {
      fa[t] = fragld(sA, wm * 64 + t * 16 + kr, kq * 8);
      fb[t] = fragld(sB, wn * 64 + t * 16 + kr, kq * 8);
    }
#pragma unroll
    for (int p = 0; p < 4; ++p)
#pragma unroll
      for (int q = 0; q < 4; ++q)
        ac[p][q] = __builtin_amdgcn_mfma_f32_16x16x32_bf16(fa[p], fb[q], ac[p][q], 0, 0, 0);
    __syncthreads();
  }
#pragma unroll
  for (int p = 0; p < 4; ++p)
#pragma unroll
    for (int q = 0; q < 4; ++q)
#pragma unroll
      for (int r = 0; r < 4; ++r) {
        size_t m = bm + wm * 64 + p * 16 + kq * 4 + r;
        size_t n = bn + wn * 64 + q * 16 + kr;
        Out[m * N_DIM + n] = ac[p][q][r] * rbuf[m];
      }
}

// ---------------- scan: 3-phase, emits h (bf16) over Ib ----------------
__global__ __launch_bounds__(256) void k_scan1(const bf16* __restrict__ Ib, const bf16* __restrict__ Fb,
                                               float* __restrict__ aggP, float* __restrict__ aggH) {
  int t = blockIdx.x * 256 + threadIdx.x;
  int e = t & (N_DIM - 1);
  int rest = t >> 11;
  int b = rest & 3;
  int c = rest >> 2;
  size_t base = ((size_t)b * S_LEN + (size_t)c * CLEN) * N_DIM + e;
  float h = 0.f, P = 1.f;
  for (int s = 0; s < CLEN; ++s) {
    size_t i = base + (size_t)s * N_DIM;
    float iv = __bfloat162float(Ib[i]);
    float fv = __bfloat162float(Fb[i]);
    float a = sigm(fv);
    float bv = iv * sigm(iv) * (1.f - a);
    h = fmaf(a, h, bv);
    P *= a;
  }
  size_t row = (size_t)b * N_DIM + e;
  aggP[row * NCHUNK + c] = P;
  aggH[row * NCHUNK + c] = h;
}

__global__ __launch_bounds__(256) void k_scan2(float* __restrict__ aggP, float* __restrict__ aggH) {
  size_t row = (size_t)blockIdx.x * 256 + threadIdx.x;
  float carry = 0.f;
  size_t base = row * NCHUNK;
  for (int c = 0; c < NCHUNK; ++c) {
    float P = aggP[base + c], hh = aggH[base + c];
    aggP[base + c] = carry;
    carry = fmaf(P, carry, hh);
  }
}

__global__ __launch_bounds__(256) void k_scan3(bf16* __restrict__ Ib, const bf16* __restrict__ Fb,
                                               const float* __restrict__ aggPre) {
  int t = blockIdx.x * 256 + threadIdx.x;
  int e = t & (N_DIM - 1);
  int rest = t >> 11;
  int b = rest & 3;
  int c = rest >> 2;
  size_t base = ((size_t)b * S_LEN + (size_t)c * CLEN) * N_DIM + e;
  size_t row = (size_t)b * N_DIM + e;
  float h = aggPre[row * NCHUNK + c];
  for (int s = 0; s < CLEN; ++s) {
    size_t i = base + (size_t)s * N_DIM;
    float iv = __bfloat162float(Ib[i]);
    float fv = __bfloat162float(Fb[i]);
    float a = sigm(fv);
    float bv = iv * sigm(iv) * (1.f - a);
    h = fmaf(a, h, bv);
    Ib[i] = __float2bfloat16(h);   // h (gating applied in k_gemm_g epilogue)
  }
}

// ---------------- per-row rms scale over xg (in Fb) ----------------
__global__ __launch_bounds__(256) void k_rownorm(const bf16* __restrict__ XG, float* __restrict__ rbuf) {
  size_t m = blockIdx.x;
  const bf16* rowp = XG + m * N_DIM;
  float ss = 0.f;
  for (int j = threadIdx.x; j < N_DIM; j += 256) {
    float v = __bfloat162float(rowp[j]);
    ss = fmaf(v, v, ss);
  }
#pragma unroll
  for (int off = 32; off > 0; off >>= 1) ss += __shfl_down(ss, off, 64);
  __shared__ float red[4];
  if ((threadIdx.x & 63) == 0) red[threadIdx.x >> 6] = ss;
  __syncthreads();
  if (threadIdx.x == 0) {
    float tot = red[0] + red[1] + red[2] + red[3];
    rbuf[m] = rsqrtf(tot * (1.f / N_DIM) + EPSV);
  }
}

extern "C" void kernel_launch(void* const* d_in, const int* in_sizes, int n_in,
                              void* d_out, int out_size, void* d_ws, size_t ws_size,
                              hipStream_t stream) {
  const float* x  = (const float*)d_in[0];
  const float* Wi = (const float*)d_in[1];
  const float* Wf = (const float*)d_in[2];
  const float* Wg = (const float*)d_in[3];
  const float* wn = (const float*)d_in[4];
  const float* Wo = (const float*)d_in[5];
  float* out = (float*)d_out;

  const size_t actB = (size_t)M_DIM * N_DIM * sizeof(bf16);   // 64 MiB
  const size_t wB   = (size_t)N_DIM * K_DIM * sizeof(bf16);   // 8 MiB
  char* ws = (char*)d_ws;
  bf16* Xb  = (bf16*)ws;    ws += actB;   // x in bf16
  bf16* Ibuf= (bf16*)ws;    ws += actB;   // raw i -> h
  bf16* Fbuf= (bf16*)ws;    ws += actB;   // raw f -> xg
  bf16* W1b = (bf16*)ws;    ws += wB;     // Wi, later Wg
  bf16* W2b = (bf16*)ws;    ws += wB;     // Wf, later Wo*w_norm
  float* aggP = (float*)ws; ws += (size_t)4 * N_DIM * NCHUNK * sizeof(float);
  float* aggH = (float*)ws; ws += (size_t)4 * N_DIM * NCHUNK * sizeof(float);
  float* rbuf = (float*)ws; ws += (size_t)M_DIM * sizeof(float);
  if ((size_t)(ws - (char*)d_ws) > ws_size) return;  // detectable: absmax 5.625

  dim3 gg(N_DIM / 128, M_DIM / 128), bb(256);
  k_cvt_x  <<<(M_DIM * (size_t)K_DIM) / (256 * 8), 256, 0, stream>>>(x, Xb);
  k_cvt_wif<<<((size_t)N_DIM * K_DIM) / (256 * 8), 256, 0, stream>>>(Wi, Wf, W1b, W2b);
  k_gemm_if<<<gg, bb, 0, stream>>>(Xb, W1b, W2b, Ibuf, Fbuf);
  k_scan1  <<<(4 * N_DIM * NCHUNK) / 256, 256, 0, stream>>>(Ibuf, Fbuf, aggP, aggH);
  k_scan2  <<<(4 * N_DIM) / 256, 256, 0, stream>>>(aggP, aggH);
  k_scan3  <<<(4 * N_DIM * NCHUNK) / 256, 256, 0, stream>>>(Ibuf, Fbuf, aggP);
  k_cvt_g_wos<<<((size_t)N_DIM * K_DIM) / (256 * 8), 256, 0, stream>>>(Wg, Wo, wn, W1b, W2b);
  k_gemm_g <<<gg, bb, 0, stream>>>(Xb, W1b, Ibuf, Fbuf);   // xg -> Fbuf
  k_rownorm<<<M_DIM, 256, 0, stream>>>(Fbuf, rbuf);
  k_gemm_o <<<gg, bb, 0, stream>>>(Fbuf, W2b, rbuf, out);
}

// Round 2
// 1042.716 us; speedup vs baseline: 1.2489x; 1.2194x over previous
//
#include <hip/hip_runtime.h>
#include <hip/hip_bf16.h>
#include <stdint.h>

// B=4, S=4096, D=2048. M = B*S = 16384 token rows.
// VERIFIED: inputs fp32 dict-order, OUTPUT FP32, MFMA layouts correct,
// absmax 0.03125. R0: 1302 us. R1 (XOR swizzle): conflicts 2.5e7 -> 0 but
// only 1271 us — 2-barrier structure is stage/drain-bound (m233 regime).
// R2 (this): dbuf LDS + counted vmcnt(L) pipeline, raw s_barrier (no
// compiler vmcnt(0) drain), STAGE(t+2) after read-release barrier.
// Loads never drain to 0 in steady state (T4). Expect total ~870 us.
#define M_DIM 16384
#define N_DIM 2048
#define K_DIM 2048
#define S_LEN 4096
#define NCHUNK 64
#define CLEN 64
#define EPSV 1e-5f

typedef __hip_bfloat16 bf16;
typedef __attribute__((ext_vector_type(8))) short bf16x8;
typedef __attribute__((ext_vector_type(4))) float floatx4;

#define WAITV6 asm volatile("s_waitcnt vmcnt(6)" ::: "memory")
#define WAITV4 asm volatile("s_waitcnt vmcnt(4)" ::: "memory")
#define WAITV0 asm volatile("s_waitcnt vmcnt(0)" ::: "memory")
#define WAITL0 asm volatile("s_waitcnt lgkmcnt(0)" ::: "memory")
#define MEMFENCE asm volatile("" ::: "memory")
#define SBAR() __builtin_amdgcn_s_barrier()

__device__ inline short f2b(float v) {
  __hip_bfloat16 h = __float2bfloat16(v);
  return *(short*)&h;
}
__device__ inline float sigm(float v) { return 1.f / (1.f + __expf(-v)); }

// ---- async global->LDS, 16B/lane. LDS dest = wave-uniform base + lane*16. ----
__device__ inline void async_ld16(const bf16* g, bf16* l) {
  __builtin_amdgcn_global_load_lds(
      (__attribute__((address_space(1))) void*)(void*)g,
      (__attribute__((address_space(3))) void*)(void*)l, 16, 0, 0);
}

// Stage 128x32 bf16 tile from row-major global (ld elems) into LDS [128][32],
// XOR-swizzled: physical 16B slot s at row r holds global slot s ^ ((r>>1)&3).
// LDS dest is linear (gload_lds requirement); swizzle applied by permuting the
// per-lane GLOBAL source slot (same 64B segment -> still coalesced).
// 2 gload_lds instructions per wave (= vmcnt ticks) per call.
__device__ inline void stage128x32(const bf16* gtile, bf16* sbuf, size_t ld, int lane, int w) {
#pragma unroll
  for (int j = 0; j < 2; ++j) {
    const int rseg = w * 32 + j * 16;
    const int row = rseg + (lane >> 2);
    const int slot = (lane & 3) ^ ((row >> 1) & 3);
    const bf16* g = gtile + (size_t)row * ld + (size_t)slot * 8;
    async_ld16(g, sbuf + rseg * 32);
  }
}

// Read logical slot ko/8 of row: physical slot = (ko/8) ^ ((row>>1)&3).
// Conflict-free: 8 consecutive lanes cover all 32 banks.
__device__ inline bf16x8 fragld(const bf16* sbuf, int row, int ko) {
  return *(const bf16x8*)(sbuf + row * 32 + (ko ^ (((row >> 1) & 3) << 3)));
}

// ---------------- conversions ----------------
__global__ __launch_bounds__(256) void k_cvt_x(const float* __restrict__ X, bf16* __restrict__ Xb) {
  size_t i = ((size_t)blockIdx.x * 256 + threadIdx.x) * 8;
  const float4 lo = *(const float4*)(X + i);
  const float4 hi = *(const float4*)(X + i + 4);
  bf16x8 v;
  v[0] = f2b(lo.x); v[1] = f2b(lo.y); v[2] = f2b(lo.z); v[3] = f2b(lo.w);
  v[4] = f2b(hi.x); v[5] = f2b(hi.y); v[6] = f2b(hi.z); v[7] = f2b(hi.w);
  *(bf16x8*)(Xb + i) = v;
}

// Wi -> W1b, Wf -> W2b
__global__ __launch_bounds__(256) void k_cvt_wif(const float* __restrict__ Wi, const float* __restrict__ Wf,
                                                 bf16* __restrict__ W1b, bf16* __restrict__ W2b) {
  size_t i = ((size_t)blockIdx.x * 256 + threadIdx.x) * 8;
  {
    const float4 lo = *(const float4*)(Wi + i);
    const float4 hi = *(const float4*)(Wi + i + 4);
    bf16x8 v;
    v[0] = f2b(lo.x); v[1] = f2b(lo.y); v[2] = f2b(lo.z); v[3] = f2b(lo.w);
    v[4] = f2b(hi.x); v[5] = f2b(hi.y); v[6] = f2b(hi.z); v[7] = f2b(hi.w);
    *(bf16x8*)(W1b + i) = v;
  }
  {
    const float4 lo = *(const float4*)(Wf + i);
    const float4 hi = *(const float4*)(Wf + i + 4);
    bf16x8 v;
    v[0] = f2b(lo.x); v[1] = f2b(lo.y); v[2] = f2b(lo.z); v[3] = f2b(lo.w);
    v[4] = f2b(hi.x); v[5] = f2b(hi.y); v[6] = f2b(hi.z); v[7] = f2b(hi.w);
    *(bf16x8*)(W2b + i) = v;
  }
}

// Wg -> W1b (reuse), Wo*w_norm -> W2b (reuse). Runs after k_gemm_if (stream order).
__global__ __launch_bounds__(256) void k_cvt_g_wos(const float* __restrict__ Wg, const float* __restrict__ Wo,
                                                   const float* __restrict__ wn,
                                                   bf16* __restrict__ W1b, bf16* __restrict__ W2b) {
  size_t i = ((size_t)blockIdx.x * 256 + threadIdx.x) * 8;
  {
    const float4 lo = *(const float4*)(Wg + i);
    const float4 hi = *(const float4*)(Wg + i + 4);
    bf16x8 v;
    v[0] = f2b(lo.x); v[1] = f2b(lo.y); v[2] = f2b(lo.z); v[3] = f2b(lo.w);
    v[4] = f2b(hi.x); v[5] = f2b(hi.y); v[6] = f2b(hi.z); v[7] = f2b(hi.w);
    *(bf16x8*)(W1b + i) = v;
  }
  {
    const float4 lo = *(const float4*)(Wo + i);
    const float4 hi = *(const float4*)(Wo + i + 4);
    const int e = (int)(i & (N_DIM - 1));
    bf16x8 v;
    v[0] = f2b(lo.x * wn[e + 0]); v[1] = f2b(lo.y * wn[e + 1]);
    v[2] = f2b(lo.z * wn[e + 2]); v[3] = f2b(lo.w * wn[e + 3]);
    v[4] = f2b(hi.x * wn[e + 4]); v[5] = f2b(hi.y * wn[e + 5]);
    v[6] = f2b(hi.z * wn[e + 6]); v[7] = f2b(hi.w * wn[e + 7]);
    *(bf16x8*)(W2b + i) = v;
  }
}

// ---------------- GEMM 1: i,f fused, dbuf + counted-vmcnt pipeline ----------------
// Per K-step per wave: 6 gload_lds (3 matrices x 2). Steady-state wait = vmcnt(6).
__global__ __launch_bounds__(256) void k_gemm_if(
    const bf16* __restrict__ Xb, const bf16* __restrict__ Wib, const bf16* __restrict__ Wfb,
    bf16* __restrict__ Ib, bf16* __restrict__ Fb) {
  __shared__ __align__(16) bf16 sA[2][128 * 32];
  __shared__ __align__(16) bf16 sI[2][128 * 32];
  __shared__ __align__(16) bf16 sF[2][128 * 32];
  const int tid = threadIdx.x, lane = tid & 63, w = tid >> 6;
  const int wm = w & 1, wn = w >> 1;
  const size_t bm = (size_t)blockIdx.y * 128, bn = (size_t)blockIdx.x * 128;
  const int kq = lane >> 4, kr = lane & 15;
  const bf16* gA = Xb + bm * K_DIM;
  const bf16* gI = Wib + bn * K_DIM;
  const bf16* gF = Wfb + bn * K_DIM;
  floatx4 ai[4][4], af[4][4];
#pragma unroll
  for (int p = 0; p < 4; ++p)
#pragma unroll
    for (int q = 0; q < 4; ++q) {
      ai[p][q] = floatx4{0.f, 0.f, 0.f, 0.f};
      af[p][q] = floatx4{0.f, 0.f, 0.f, 0.f};
    }
  // prologue: tiles 0 and 1 in flight
  stage128x32(gA + 0, &sA[0][0], K_DIM, lane, w);
  stage128x32(gI + 0, &sI[0][0], K_DIM, lane, w);
  stage128x32(gF + 0, &sF[0][0], K_DIM, lane, w);
  stage128x32(gA + 32, &sA[1][0], K_DIM, lane, w);
  stage128x32(gI + 32, &sI[1][0], K_DIM, lane, w);
  stage128x32(gF + 32, &sF[1][0], K_DIM, lane, w);
  for (int t = 0; t < 64; ++t) {
    const int cur = t & 1;
    if (t < 63) { WAITV6; } else { WAITV0; }   // tile t done; t+1 stays in flight
    SBAR(); MEMFENCE;                           // all waves' tile-t loads visible
    bf16x8 fa[4], fi[4], ff[4];
#pragma unroll
    for (int u = 0; u < 4; ++u) {
      fa[u] = fragld(&sA[cur][0], wm * 64 + u * 16 + kr, kq * 8);
      fi[u] = fragld(&sI[cur][0], wn * 64 + u * 16 + kr, kq * 8);
      ff[u] = fragld(&sF[cur][0], wn * 64 + u * 16 + kr, kq * 8);
    }
#pragma unroll
    for (int p = 0; p < 4; ++p)
#pragma unroll
      for (int q = 0; q < 4; ++q) {
        ai[p][q] = __builtin_amdgcn_mfma_f32_16x16x32_bf16(fa[p], fi[q], ai[p][q], 0, 0, 0);
        af[p][q] = __builtin_amdgcn_mfma_f32_16x16x32_bf16(fa[p], ff[q], af[p][q], 0, 0, 0);
      }
    WAITL0;                                     // this wave's reads of buf[cur] done
    SBAR(); MEMFENCE;                           // all waves done reading buf[cur]
    if (t + 2 < 64) {                           // overwrite buf[cur] with tile t+2
      const int k0 = (t + 2) * 32;
      stage128x32(gA + k0, &sA[cur][0], K_DIM, lane, w);
      stage128x32(gI + k0, &sI[cur][0], K_DIM, lane, w);
      stage128x32(gF + k0, &sF[cur][0], K_DIM, lane, w);
    }
  }
#pragma unroll
  for (int p = 0; p < 4; ++p)
#pragma unroll
    for (int q = 0; q < 4; ++q)
#pragma unroll
      for (int r = 0; r < 4; ++r) {
        size_t m = bm + wm * 64 + p * 16 + kq * 4 + r;
        size_t n = bn + wn * 64 + q * 16 + kr;
        Ib[m * N_DIM + n] = __float2bfloat16(ai[p][q][r]);
        Fb[m * N_DIM + n] = __float2bfloat16(af[p][q][r]);
      }
}

// ---------------- GEMM 2: g + fused gate xg = h*silu(g), dbuf pipeline ----------------
__global__ __launch_bounds__(256) void k_gemm_g(
    const bf16* __restrict__ Xb, const bf16* __restrict__ Wgb, const bf16* __restrict__ Hb,
    bf16* __restrict__ XGout) {
  __shared__ __align__(16) bf16 sA[2][128 * 32];
  __shared__ __align__(16) bf16 sB[2][128 * 32];
  const int tid = threadIdx.x, lane = tid & 63, w = tid >> 6;
  const int wm = w & 1, wn = w >> 1;
  const size_t bm = (size_t)blockIdx.y * 128, bn = (size_t)blockIdx.x * 128;
  const int kq = lane >> 4, kr = lane & 15;
  const bf16* gA = Xb + bm * K_DIM;
  const bf16* gB = Wgb + bn * K_DIM;
  floatx4 ac[4][4];
#pragma unroll
  for (int p = 0; p < 4; ++p)
#pragma unroll
    for (int q = 0; q < 4; ++q) ac[p][q] = floatx4{0.f, 0.f, 0.f, 0.f};
  stage128x32(gA + 0, &sA[0][0], K_DIM, lane, w);
  stage128x32(gB + 0, &sB[0][0], K_DIM, lane, w);
  stage128x32(gA + 32, &sA[1][0], K_DIM, lane, w);
  stage128x32(gB + 32, &sB[1][0], K_DIM, lane, w);
  for (int t = 0; t < 64; ++t) {
    const int cur = t & 1;
    if (t < 63) { WAITV4; } else { WAITV0; }
    SBAR(); MEMFENCE;
    bf16x8 fa[4], fb[4];
#pragma unroll
    for (int u = 0; u < 4; ++u) {
      fa[u] = fragld(&sA[cur][0], wm * 64 + u * 16 + kr, kq * 8);
      fb[u] = fragld(&sB[cur][0], wn * 64 + u * 16 + kr, kq * 8);
    }
#pragma unroll
    for (int p = 0; p < 4; ++p)
#pragma unroll
      for (int q = 0; q < 4; ++q)
        ac[p][q] = __builtin_amdgcn_mfma_f32_16x16x32_bf16(fa[p], fb[q], ac[p][q], 0, 0, 0);
    WAITL0;
    SBAR(); MEMFENCE;
    if (t + 2 < 64) {
      const int k0 = (t + 2) * 32;
      stage128x32(gA + k0, &sA[cur][0], K_DIM, lane, w);
      stage128x32(gB + k0, &sB[cur][0], K_DIM, lane, w);
    }
  }
#pragma unroll
  for (int p = 0; p < 4; ++p)
#pragma unroll
    for (int q = 0; q < 4; ++q)
#pragma unroll
      for (int r = 0; r < 4; ++r) {
        size_t m = bm + wm * 64 + p * 16 + kq * 4 + r;
        size_t n = bn + wn * 64 + q * 16 + kr;
        float gv = ac[p][q][r];
        float hv = __bfloat162float(Hb[m * N_DIM + n]);
        XGout[m * N_DIM + n] = __float2bfloat16(hv * gv * sigm(gv));
      }
}

// ---------------- GEMM 3: out = (xg·Wo'^T) * r[m] -> FP32, dbuf pipeline ----------------
__global__ __launch_bounds__(256) void k_gemm_o(
    const bf16* __restrict__ XG, const bf16* __restrict__ WoS, const float* __restrict__ rbuf,
    float* __restrict__ Out) {
  __shared__ __align__(16) bf16 sA[2][128 * 32];
  __shared__ __align__(16) bf16 sB[2][128 * 32];
  const int tid = threadIdx.x, lane = tid & 63, w = tid >> 6;
  const int wm = w & 1, wn = w >> 1;
  const size_t bm = (size_t)blockIdx.y * 128, bn = (size_t)blockIdx.x * 128;
  const int kq = lane >> 4, kr = lane & 15;
  const bf16* gA = XG + bm * K_DIM;
  const bf16* gB = WoS + bn * K_DIM;
  floatx4 ac[4][4];
#pragma unroll
  for (int p = 0; p < 4; ++p)
#pragma unroll
    for (int q = 0; q < 4; ++q) ac[p][q] = floatx4{0.f, 0.f, 0.f, 0.f};
  stage128x32(gA + 0, &sA[0][0], K_DIM, lane, w);
  stage128x32(gB + 0, &sB[0][0], K_DIM, lane, w);
  stage128x32(gA + 32, &sA[1][0], K_DIM, lane, w);
  stage128x32(gB + 32, &sB[1][0], K_DIM, lane, w);
  for (int t = 0; t < 64; ++t) {
    const int cur = t & 1;
    if (t < 63) { WAITV4; } else { WAITV0; }
    SBAR(); MEMFENCE;
    bf16x8 fa[4], fb[4];
#pragma unroll
    for (int u = 0; u < 4; ++u) {
      fa[u] = fragld(&sA[cur][0], wm * 64 + u * 16 + kr, kq * 8);
      fb[u] = fragld(&sB[cur][0], wn * 64 + u * 16 + kr, kq * 8);
    }
#pragma unroll
    for (int p = 0; p < 4; ++p)
#pragma unroll
      for (int q = 0; q < 4; ++q)
        ac[p][q] = __builtin_amdgcn_mfma_f32_16x16x32_bf16(fa[p], fb[q], ac[p][q], 0, 0, 0);
    WAITL0;
    SBAR(); MEMFENCE;
    if (t + 2 < 64) {
      const int k0 = (t + 2) * 32;
      stage128x32(gA + k0, &sA[cur][0], K_DIM, lane, w);
      stage128x32(gB + k0, &sB[cur][0], K_DIM, lane, w);
    }
  }
#pragma unroll
  for (int p = 0; p < 4; ++p)
#pragma unroll
    for (int q = 0; q < 4; ++q)
#pragma unroll
      for (int r = 0; r < 4; ++r) {
        size_t m = bm + wm * 64 + p * 16 + kq * 4 + r;
        size_t n = bn + wn * 64 + q * 16 + kr;
        Out[m * N_DIM + n] = ac[p][q][r] * rbuf[m];
      }
}

// ---------------- scan: 3-phase, emits h (bf16) over Ib ----------------
__global__ __launch_bounds__(256) void k_scan1(const bf16* __restrict__ Ib, const bf16* __restrict__ Fb,
                                               float* __restrict__ aggP, float* __restrict__ aggH) {
  int t = blockIdx.x * 256 + threadIdx.x;
  int e = t & (N_DIM - 1);
  int rest = t >> 11;
  int b = rest & 3;
  int c = rest >> 2;
  size_t base = ((size_t)b * S_LEN + (size_t)c * CLEN) * N_DIM + e;
  float h = 0.f, P = 1.f;
  for (int s = 0; s < CLEN; ++s) {
    size_t i = base + (size_t)s * N_DIM;
    float iv = __bfloat162float(Ib[i]);
    float fv = __bfloat162float(Fb[i]);
    float a = sigm(fv);
    float bv = iv * sigm(iv) * (1.f - a);
    h = fmaf(a, h, bv);
    P *= a;
  }
  size_t row = (size_t)b * N_DIM + e;
  aggP[row * NCHUNK + c] = P;
  aggH[row * NCHUNK + c] = h;
}

__global__ __launch_bounds__(256) void k_scan2(float* __restrict__ aggP, float* __restrict__ aggH) {
  size_t row = (size_t)blockIdx.x * 256 + threadIdx.x;
  float carry = 0.f;
  size_t base = row * NCHUNK;
  for (int c = 0; c < NCHUNK; ++c) {
    float P = aggP[base + c], hh = aggH[base + c];
    aggP[base + c] = carry;
    carry = fmaf(P, carry, hh);
  }
}

__global__ __launch_bounds__(256) void k_scan3(bf16* __restrict__ Ib, const bf16* __restrict__ Fb,
                                               const float* __restrict__ aggPre) {
  int t = blockIdx.x * 256 + threadIdx.x;
  int e = t & (N_DIM - 1);
  int rest = t >> 11;
  int b = rest & 3;
  int c = rest >> 2;
  size_t base = ((size_t)b * S_LEN + (size_t)c * CLEN) * N_DIM + e;
  size_t row = (size_t)b * N_DIM + e;
  float h = aggPre[row * NCHUNK + c];
  for (int s = 0; s < CLEN; ++s) {
    size_t i = base + (size_t)s * N_DIM;
    float iv = __bfloat162float(Ib[i]);
    float fv = __bfloat162float(Fb[i]);
    float a = sigm(fv);
    float bv = iv * sigm(iv) * (1.f - a);
    h = fmaf(a, h, bv);
    Ib[i] = __float2bfloat16(h);   // h (gating applied in k_gemm_g epilogue)
  }
}

// ---------------- per-row rms scale over xg (in Fb) ----------------
__global__ __launch_bounds__(256) void k_rownorm(const bf16* __restrict__ XG, float* __restrict__ rbuf) {
  size_t m = blockIdx.x;
  const bf16* rowp = XG + m * N_DIM;
  float ss = 0.f;
  for (int j = threadIdx.x; j < N_DIM; j += 256) {
    float v = __bfloat162float(rowp[j]);
    ss = fmaf(v, v, ss);
  }
#pragma unroll
  for (int off = 32; off > 0; off >>= 1) ss += __shfl_down(ss, off, 64);
  __shared__ float red[4];
  if ((threadIdx.x & 63) == 0) red[threadIdx.x >> 6] = ss;
  __syncthreads();
  if (threadIdx.x == 0) {
    float tot = red[0] + red[1] + red[2] + red[3];
    rbuf[m] = rsqrtf(tot * (1.f / N_DIM) + EPSV);
  }
}

extern "C" void kernel_launch(void* const* d_in, const int* in_sizes, int n_in,
                              void* d_out, int out_size, void* d_ws, size_t ws_size,
                              hipStream_t stream) {
  const float* x  = (const float*)d_in[0];
  const float* Wi = (const float*)d_in[1];
  const float* Wf = (const float*)d_in[2];
  const float* Wg = (const float*)d_in[3];
  const float* wn = (const float*)d_in[4];
  const float* Wo = (const float*)d_in[5];
  float* out = (float*)d_out;

  const size_t actB = (size_t)M_DIM * N_DIM * sizeof(bf16);   // 64 MiB
  const size_t wB   = (size_t)N_DIM * K_DIM * sizeof(bf16);   // 8 MiB
  char* ws = (char*)d_ws;
  bf16* Xb  = (bf16*)ws;    ws += actB;   // x in bf16
  bf16* Ibuf= (bf16*)ws;    ws += actB;   // raw i -> h
  bf16* Fbuf= (bf16*)ws;    ws += actB;   // raw f -> xg
  bf16* W1b = (bf16*)ws;    ws += wB;     // Wi, later Wg
  bf16* W2b = (bf16*)ws;    ws += wB;     // Wf, later Wo*w_norm
  float* aggP = (float*)ws; ws += (size_t)4 * N_DIM * NCHUNK * sizeof(float);
  float* aggH = (float*)ws; ws += (size_t)4 * N_DIM * NCHUNK * sizeof(float);
  float* rbuf = (float*)ws; ws += (size_t)M_DIM * sizeof(float);
  if ((size_t)(ws - (char*)d_ws) > ws_size) return;  // detectable: absmax 5.625

  dim3 gg(N_DIM / 128, M_DIM / 128), bb(256);
  k_cvt_x  <<<(M_DIM * (size_t)K_DIM) / (256 * 8), 256, 0, stream>>>(x, Xb);
  k_cvt_wif<<<((size_t)N_DIM * K_DIM) / (256 * 8), 256, 0, stream>>>(Wi, Wf, W1b, W2b);
  k_gemm_if<<<gg, bb, 0, stream>>>(Xb, W1b, W2b, Ibuf, Fbuf);
  k_scan1  <<<(4 * N_DIM * NCHUNK) / 256, 256, 0, stream>>>(Ibuf, Fbuf, aggP, aggH);
  k_scan2  <<<(4 * N_DIM) / 256, 256, 0, stream>>>(aggP, aggH);
  k_scan3  <<<(4 * N_DIM * NCHUNK) / 256, 256, 0, stream>>>(Ibuf, Fbuf, aggP);
  k_cvt_g_wos<<<((size_t)N_DIM * K_DIM) / (256 * 8), 256, 0, stream>>>(Wg, Wo, wn, W1b, W2b);
  k_gemm_g <<<gg, bb, 0, stream>>>(Xb, W1b, Ibuf, Fbuf);   // xg -> Fbuf
  k_rownorm<<<M_DIM, 256, 0, stream>>>(Fbuf, rbuf);
  k_gemm_o <<<gg, bb, 0, stream>>>(Fbuf, W2b, rbuf, out);
}

// Round 3
// 896.861 us; speedup vs baseline: 1.4520x; 1.1626x over previous
//
#include <hip/hip_runtime.h>
#include <hip/hip_bf16.h>
#include <stdint.h>

// B=4, S=4096, D=2048. M = B*S = 16384 token rows.
// R0 1302us -> R1 swizzle (conflicts 2.5e7->0, 1271us) -> R2 counted-vmcnt dbuf
// (1043us, gemm_if 319us = 860 TF = the 128^2/2-barrier ceiling).
// R3 (this): 256^2 tile, BK=64, 8 waves, dbuf + counted vmcnt(8); release
// barrier placed mid-iteration so stage(t+2) overlaps MFMA half-2; slot-XOR
// swizzle for 128B rows; T5 setprio; T1 bijective XCD swizzle; gemm_if as one
// N=4096 GEMM over concat [Wi;Wf]; scans/rownorm vectorized (G13).
#define M_DIM 16384
#define N_DIM 2048
#define K_DIM 2048
#define S_LEN 4096
#define NCHUNK 64
#define CLEN 64
#define EPSV 1e-5f
#define TILE (256 * 64)   // elems per LDS tile buffer

typedef __hip_bfloat16 bf16;
typedef __attribute__((ext_vector_type(8))) short bf16x8;
typedef __attribute__((ext_vector_type(4))) float floatx4;
typedef __attribute__((ext_vector_type(4))) unsigned short u16x4;

#define WAITV8 asm volatile("s_waitcnt vmcnt(8)" ::: "memory")
#define WAITV0 asm volatile("s_waitcnt vmcnt(0)" ::: "memory")
#define WAITL0 asm volatile("s_waitcnt lgkmcnt(0)" ::: "memory")
#define MEMFENCE asm volatile("" ::: "memory")
#define SBAR() __builtin_amdgcn_s_barrier()

__device__ inline short f2b(float v) {
  __hip_bfloat16 h = __float2bfloat16(v);
  return *(short*)&h;
}
__device__ inline float b2f(unsigned short u) {
  union { unsigned int i; float f; } x;
  x.i = (unsigned int)u << 16;
  return x.f;
}
__device__ inline float sigm(float v) { return 1.f / (1.f + __expf(-v)); }

// ---- async global->LDS, 16B/lane. LDS dest = wave-uniform base + lane*16. ----
__device__ inline void async_ld16(const bf16* g, bf16* l) {
  __builtin_amdgcn_global_load_lds(
      (__attribute__((address_space(1))) void*)(void*)g,
      (__attribute__((address_space(3))) void*)(void*)l, 16, 0, 0);
}

// Stage 256x64 bf16 tile (row = 128 B = 8 x 16B slots) into linear LDS.
// Swizzle: phys slot p at row r holds logical slot p ^ (r&7) — applied by
// permuting the per-lane GLOBAL source slot (rule #21: both-sides-or-neither;
// LDS dest stays linear for gload_lds). 4 gload_lds per thread per call.
__device__ inline void stage256x64(const bf16* gtile, bf16* sbuf, int lane, int w) {
#pragma unroll
  for (int j = 0; j < 4; ++j) {
    const int rbase = j * 64 + w * 8;          // 8 rows per wave-instruction
    const int row = rbase + (lane >> 3);
    const int ls = (lane & 7) ^ (row & 7);     // logical slot for phys slot (lane&7)
    const bf16* g = gtile + (size_t)row * K_DIM + (size_t)ls * 8;
    async_ld16(g, sbuf + rbase * 64);
  }
}

// Read logical k-slot (ks*4+kq) of row: phys = logical ^ (row&7).
// Wave bank math: 16 lanes per kq group hit 8 slots x 2 = 2-way (free, m136).
__device__ inline bf16x8 fragld64(const bf16* sbuf, int row, int ks, int kq) {
  const int slot = (ks * 4 + kq) ^ (row & 7);
  return *(const bf16x8*)(sbuf + row * 64 + slot * 8);
}

// ---- 256x256 BK=64 dbuf K-loop core. 8 waves (2m x 4n), per-wave out 128x64.
// Per K-tile: WAITV8 -> SBAR -> [B frags + A-half0 reads interleave MFMA half0]
// -> A-half1 reads -> lgkm0 -> SBAR(release) -> stage(t+2) -> MFMA half1.
__device__ __forceinline__ void gemm_core(
    const bf16* gA, const bf16* gB, bf16* sA, bf16* sB,
    floatx4 (&acc)[8][4], int lane, int w, int wm, int wn, int kq, int kr) {
  stage256x64(gA, sA, lane, w);
  stage256x64(gB, sB, lane, w);
  stage256x64(gA + 64, sA + TILE, lane, w);
  stage256x64(gB + 64, sB + TILE, lane, w);
  for (int t = 0; t < 32; ++t) {
    const int cur = t & 1;
    bf16* bufA = sA + cur * TILE;
    bf16* bufB = sB + cur * TILE;
    if (t < 31) { WAITV8; } else { WAITV0; }   // tile t landed; t+1 stays in flight
    SBAR(); MEMFENCE;                           // cross-wave visibility of buf[cur]
    bf16x8 fb[4][2];
#pragma unroll
    for (int q = 0; q < 4; ++q)
#pragma unroll
      for (int ks = 0; ks < 2; ++ks)
        fb[q][ks] = fragld64(bufB, wn * 64 + q * 16 + kr, ks, kq);
    __builtin_amdgcn_s_setprio(1);
#pragma unroll
    for (int p = 0; p < 4; ++p) {
      bf16x8 fa0 = fragld64(bufA, wm * 128 + p * 16 + kr, 0, kq);
      bf16x8 fa1 = fragld64(bufA, wm * 128 + p * 16 + kr, 1, kq);
#pragma unroll
      for (int q = 0; q < 4; ++q) {
        acc[p][q] = __builtin_amdgcn_mfma_f32_16x16x32_bf16(fa0, fb[q][0], acc[p][q], 0, 0, 0);
        acc[p][q] = __builtin_amdgcn_mfma_f32_16x16x32_bf16(fa1, fb[q][1], acc[p][q], 0, 0, 0);
      }
    }
    __builtin_amdgcn_s_setprio(0);
    bf16x8 fa2[4][2];
#pragma unroll
    for (int p = 0; p < 4; ++p)
#pragma unroll
      for (int ks = 0; ks < 2; ++ks)
        fa2[p][ks] = fragld64(bufA, wm * 128 + (p + 4) * 16 + kr, ks, kq);
    WAITL0;                                     // this wave's reads of buf[cur] done
    SBAR(); MEMFENCE;                           // all waves done reading buf[cur]
    if (t + 2 < 32) {                           // stage t+2 flies under MFMA half1
      stage256x64(gA + (t + 2) * 64, sA + cur * TILE, lane, w);
      stage256x64(gB + (t + 2) * 64, sB + cur * TILE, lane, w);
    }
    __builtin_amdgcn_s_setprio(1);
#pragma unroll
    for (int p = 0; p < 4; ++p)
#pragma unroll
      for (int q = 0; q < 4; ++q) {
        acc[p + 4][q] = __builtin_amdgcn_mfma_f32_16x16x32_bf16(fa2[p][0], fb[q][0], acc[p + 4][q], 0, 0, 0);
        acc[p + 4][q] = __builtin_amdgcn_mfma_f32_16x16x32_bf16(fa2[p][1], fb[q][1], acc[p + 4][q], 0, 0, 0);
      }
    __builtin_amdgcn_s_setprio(0);
  }
}

// ---------------- conversions ----------------
__global__ __launch_bounds__(256) void k_cvt_x(const float* __restrict__ X, bf16* __restrict__ Xb) {
  size_t i = ((size_t)blockIdx.x * 256 + threadIdx.x) * 8;
  const float4 lo = *(const float4*)(X + i);
  const float4 hi = *(const float4*)(X + i + 4);
  bf16x8 v;
  v[0] = f2b(lo.x); v[1] = f2b(lo.y); v[2] = f2b(lo.z); v[3] = f2b(lo.w);
  v[4] = f2b(hi.x); v[5] = f2b(hi.y); v[6] = f2b(hi.z); v[7] = f2b(hi.w);
  *(bf16x8*)(Xb + i) = v;
}

// Wi -> Wif[0:NK), Wf -> Wif[NK:2NK)  (concat weight for the fused i,f GEMM)
__global__ __launch_bounds__(256) void k_cvt_wif(const float* __restrict__ Wi, const float* __restrict__ Wf,
                                                 bf16* __restrict__ Wif) {
  size_t i = ((size_t)blockIdx.x * 256 + threadIdx.x) * 8;
  const size_t NK = (size_t)N_DIM * K_DIM;
  {
    const float4 lo = *(const float4*)(Wi + i);
    const float4 hi = *(const float4*)(Wi + i + 4);
    bf16x8 v;
    v[0] = f2b(lo.x); v[1] = f2b(lo.y); v[2] = f2b(lo.z); v[3] = f2b(lo.w);
    v[4] = f2b(hi.x); v[5] = f2b(hi.y); v[6] = f2b(hi.z); v[7] = f2b(hi.w);
    *(bf16x8*)(Wif + i) = v;
  }
  {
    const float4 lo = *(const float4*)(Wf + i);
    const float4 hi = *(const float4*)(Wf + i + 4);
    bf16x8 v;
    v[0] = f2b(lo.x); v[1] = f2b(lo.y); v[2] = f2b(lo.z); v[3] = f2b(lo.w);
    v[4] = f2b(hi.x); v[5] = f2b(hi.y); v[6] = f2b(hi.z); v[7] = f2b(hi.w);
    *(bf16x8*)(Wif + NK + i) = v;
  }
}

// Wg -> W1b (reuse Wif lo half), Wo*w_norm -> W2b (reuse Wif hi half).
__global__ __launch_bounds__(256) void k_cvt_g_wos(const float* __restrict__ Wg, const float* __restrict__ Wo,
                                                   const float* __restrict__ wn,
                                                   bf16* __restrict__ W1b, bf16* __restrict__ W2b) {
  size_t i = ((size_t)blockIdx.x * 256 + threadIdx.x) * 8;
  {
    const float4 lo = *(const float4*)(Wg + i);
    const float4 hi = *(const float4*)(Wg + i + 4);
    bf16x8 v;
    v[0] = f2b(lo.x); v[1] = f2b(lo.y); v[2] = f2b(lo.z); v[3] = f2b(lo.w);
    v[4] = f2b(hi.x); v[5] = f2b(hi.y); v[6] = f2b(hi.z); v[7] = f2b(hi.w);
    *(bf16x8*)(W1b + i) = v;
  }
  {
    const float4 lo = *(const float4*)(Wo + i);
    const float4 hi = *(const float4*)(Wo + i + 4);
    const int e = (int)(i & (N_DIM - 1));
    bf16x8 v;
    v[0] = f2b(lo.x * wn[e + 0]); v[1] = f2b(lo.y * wn[e + 1]);
    v[2] = f2b(lo.z * wn[e + 2]); v[3] = f2b(lo.w * wn[e + 3]);
    v[4] = f2b(hi.x * wn[e + 4]); v[5] = f2b(hi.y * wn[e + 5]);
    v[6] = f2b(hi.z * wn[e + 6]); v[7] = f2b(hi.w * wn[e + 7]);
    *(bf16x8*)(W2b + i) = v;
  }
}

// ---------------- GEMM 1: [M,K] x Wif^T -> i (n<2048) and f (n>=2048) ----------------
__global__ __launch_bounds__(512) void k_gemm_if(
    const bf16* __restrict__ Xb, const bf16* __restrict__ Wif,
    bf16* __restrict__ Ib, bf16* __restrict__ Fb) {
  __shared__ __align__(16) bf16 sA[2 * TILE];
  __shared__ __align__(16) bf16 sB[2 * TILE];
  const int tid = threadIdx.x, lane = tid & 63, w = tid >> 6;
  const int wm = w >> 2, wn = w & 3;
  const int kq = lane >> 4, kr = lane & 15;
  const int nwg = gridDim.x;                        // 1024, %8==0
  const int id = blockIdx.x;
  const int wg = (id & 7) * (nwg >> 3) + (id >> 3); // bijective XCD swizzle
  const size_t bm = (size_t)(wg >> 4) * 256;        // 64 m-blocks
  const int bn = (wg & 15) * 256;                   // 16 n-blocks over N=4096
  floatx4 acc[8][4];
#pragma unroll
  for (int p = 0; p < 8; ++p)
#pragma unroll
    for (int q = 0; q < 4; ++q) acc[p][q] = floatx4{0.f, 0.f, 0.f, 0.f};
  gemm_core(Xb + bm * K_DIM, Wif + (size_t)bn * K_DIM, sA, sB, acc, lane, w, wm, wn, kq, kr);
  bf16* dst = (bn < N_DIM) ? Ib : Fb;               // block-uniform routing
  const int nbase = (bn & (N_DIM - 1)) + wn * 64;
#pragma unroll
  for (int p = 0; p < 8; ++p)
#pragma unroll
    for (int q = 0; q < 4; ++q)
#pragma unroll
      for (int r = 0; r < 4; ++r) {
        size_t m = bm + wm * 128 + p * 16 + kq * 4 + r;
        dst[m * N_DIM + nbase + q * 16 + kr] = __float2bfloat16(acc[p][q][r]);
      }
}

// ---------------- GEMM 2: g + fused gate xg = h*silu(g) ----------------
__global__ __launch_bounds__(512) void k_gemm_g(
    const bf16* __restrict__ Xb, const bf16* __restrict__ Wgb, const bf16* __restrict__ Hb,
    bf16* __restrict__ XGout) {
  __shared__ __align__(16) bf16 sA[2 * TILE];
  __shared__ __align__(16) bf16 sB[2 * TILE];
  const int tid = threadIdx.x, lane = tid & 63, w = tid >> 6;
  const int wm = w >> 2, wn = w & 3;
  const int kq = lane >> 4, kr = lane & 15;
  const int nwg = gridDim.x;                        // 512, %8==0
  const int id = blockIdx.x;
  const int wg = (id & 7) * (nwg >> 3) + (id >> 3);
  const size_t bm = (size_t)(wg >> 3) * 256;
  const int bn = (wg & 7) * 256;
  floatx4 acc[8][4];
#pragma unroll
  for (int p = 0; p < 8; ++p)
#pragma unroll
    for (int q = 0; q < 4; ++q) acc[p][q] = floatx4{0.f, 0.f, 0.f, 0.f};
  gemm_core(Xb + bm * K_DIM, Wgb + (size_t)bn * K_DIM, sA, sB, acc, lane, w, wm, wn, kq, kr);
#pragma unroll
  for (int p = 0; p < 8; ++p)
#pragma unroll
    for (int q = 0; q < 4; ++q)
#pragma unroll
      for (int r = 0; r < 4; ++r) {
        size_t m = bm + wm * 128 + p * 16 + kq * 4 + r;
        size_t n = (size_t)bn + wn * 64 + q * 16 + kr;
        float gv = acc[p][q][r];
        float hv = __bfloat162float(Hb[m * N_DIM + n]);
        XGout[m * N_DIM + n] = __float2bfloat16(hv * gv * sigm(gv));
      }
}

// ---------------- GEMM 3: out = (xg·Wo'^T) * r[m] -> FP32 ----------------
__global__ __launch_bounds__(512) void k_gemm_o(
    const bf16* __restrict__ XG, const bf16* __restrict__ WoS, const float* __restrict__ rbuf,
    float* __restrict__ Out) {
  __shared__ __align__(16) bf16 sA[2 * TILE];
  __shared__ __align__(16) bf16 sB[2 * TILE];
  const int tid = threadIdx.x, lane = tid & 63, w = tid >> 6;
  const int wm = w >> 2, wn = w & 3;
  const int kq = lane >> 4, kr = lane & 15;
  const int nwg = gridDim.x;
  const int id = blockIdx.x;
  const int wg = (id & 7) * (nwg >> 3) + (id >> 3);
  const size_t bm = (size_t)(wg >> 3) * 256;
  const int bn = (wg & 7) * 256;
  floatx4 acc[8][4];
#pragma unroll
  for (int p = 0; p < 8; ++p)
#pragma unroll
    for (int q = 0; q < 4; ++q) acc[p][q] = floatx4{0.f, 0.f, 0.f, 0.f};
  gemm_core(XG + bm * K_DIM, WoS + (size_t)bn * K_DIM, sA, sB, acc, lane, w, wm, wn, kq, kr);
#pragma unroll
  for (int p = 0; p < 8; ++p)
#pragma unroll
    for (int q = 0; q < 4; ++q)
#pragma unroll
      for (int r = 0; r < 4; ++r) {
        size_t m = bm + wm * 128 + p * 16 + kq * 4 + r;
        size_t n = (size_t)bn + wn * 64 + q * 16 + kr;
        Out[m * N_DIM + n] = acc[p][q][r] * rbuf[m];
      }
}

// ---------------- scan: 3-phase, vectorized 4-elem groups (8B loads, G13) ----------------
__global__ __launch_bounds__(256) void k_scan1(const bf16* __restrict__ Ib, const bf16* __restrict__ Fb,
                                               float* __restrict__ aggP, float* __restrict__ aggH) {
  int t = blockIdx.x * 256 + threadIdx.x;        // 131072 threads
  int e4 = t & 511;                              // 512 groups of 4 elems
  int rest = t >> 9;                             // 256 = 4b x 64c
  int b = rest & 3;
  int c = rest >> 2;
  size_t base = ((size_t)b * S_LEN + (size_t)c * CLEN) * N_DIM + (size_t)e4 * 4;
  float h[4] = {0.f, 0.f, 0.f, 0.f};
  float P[4] = {1.f, 1.f, 1.f, 1.f};
  for (int s = 0; s < CLEN; ++s) {
    size_t i = base + (size_t)s * N_DIM;
    u16x4 iv = *(const u16x4*)(Ib + i);
    u16x4 fv = *(const u16x4*)(Fb + i);
#pragma unroll
    for (int j = 0; j < 4; ++j) {
      float ivf = b2f(iv[j]), fvf = b2f(fv[j]);
      float a = sigm(fvf);
      float bv = ivf * sigm(ivf) * (1.f - a);
      h[j] = fmaf(a, h[j], bv);
      P[j] *= a;
    }
  }
#pragma unroll
  for (int j = 0; j < 4; ++j) {
    size_t row = (size_t)b * N_DIM + e4 * 4 + j;
    aggP[row * NCHUNK + c] = P[j];
    aggH[row * NCHUNK + c] = h[j];
  }
}

__global__ __launch_bounds__(256) void k_scan2(float* __restrict__ aggP, float* __restrict__ aggH) {
  size_t row = (size_t)blockIdx.x * 256 + threadIdx.x;
  float carry = 0.f;
  size_t base = row * NCHUNK;
  for (int c = 0; c < NCHUNK; ++c) {
    float P = aggP[base + c], hh = aggH[base + c];
    aggP[base + c] = carry;
    carry = fmaf(P, carry, hh);
  }
}

__global__ __launch_bounds__(256) void k_scan3(bf16* __restrict__ Ib, const bf16* __restrict__ Fb,
                                               const float* __restrict__ aggPre) {
  int t = blockIdx.x * 256 + threadIdx.x;
  int e4 = t & 511;
  int rest = t >> 9;
  int b = rest & 3;
  int c = rest >> 2;
  size_t base = ((size_t)b * S_LEN + (size_t)c * CLEN) * N_DIM + (size_t)e4 * 4;
  float h[4];
#pragma unroll
  for (int j = 0; j < 4; ++j) {
    size_t row = (size_t)b * N_DIM + e4 * 4 + j;
    h[j] = aggPre[row * NCHUNK + c];
  }
  for (int s = 0; s < CLEN; ++s) {
    size_t i = base + (size_t)s * N_DIM;
    u16x4 iv = *(const u16x4*)(Ib + i);
    u16x4 fv = *(const u16x4*)(Fb + i);
    u16x4 hv;
#pragma unroll
    for (int j = 0; j < 4; ++j) {
      float ivf = b2f(iv[j]), fvf = b2f(fv[j]);
      float a = sigm(fvf);
      float bv = ivf * sigm(ivf) * (1.f - a);
      h[j] = fmaf(a, h[j], bv);
      hv[j] = (unsigned short)f2b(h[j]);
    }
    *(u16x4*)(Ib + i) = hv;    // h (gating applied in k_gemm_g epilogue)
  }
}

// ---------------- per-row rms scale over xg (vectorized bf16x8 load) ----------------
__global__ __launch_bounds__(256) void k_rownorm(const bf16* __restrict__ XG, float* __restrict__ rbuf) {
  size_t m = blockIdx.x;
  const bf16x8 v = *(const bf16x8*)(XG + m * N_DIM + (size_t)threadIdx.x * 8);
  float ss = 0.f;
#pragma unroll
  for (int j = 0; j < 8; ++j) {
    float x = b2f((unsigned short)v[j]);
    ss = fmaf(x, x, ss);
  }
#pragma unroll
  for (int off = 32; off > 0; off >>= 1) ss += __shfl_down(ss, off, 64);
  __shared__ float red[4];
  if ((threadIdx.x & 63) == 0) red[threadIdx.x >> 6] = ss;
  __syncthreads();
  if (threadIdx.x == 0) {
    float tot = red[0] + red[1] + red[2] + red[3];
    rbuf[m] = rsqrtf(tot * (1.f / N_DIM) + EPSV);
  }
}

extern "C" void kernel_launch(void* const* d_in, const int* in_sizes, int n_in,
                              void* d_out, int out_size, void* d_ws, size_t ws_size,
                              hipStream_t stream) {
  const float* x  = (const float*)d_in[0];
  const float* Wi = (const float*)d_in[1];
  const float* Wf = (const float*)d_in[2];
  const float* Wg = (const float*)d_in[3];
  const float* wn = (const float*)d_in[4];
  const float* Wo = (const float*)d_in[5];
  float* out = (float*)d_out;

  const size_t actB = (size_t)M_DIM * N_DIM * sizeof(bf16);   // 64 MiB
  const size_t wB   = (size_t)N_DIM * K_DIM * sizeof(bf16);   // 8 MiB
  char* ws = (char*)d_ws;
  bf16* Xb  = (bf16*)ws;    ws += actB;       // x in bf16
  bf16* Ibuf= (bf16*)ws;    ws += actB;       // raw i -> h
  bf16* Fbuf= (bf16*)ws;    ws += actB;       // raw f -> xg
  bf16* Wif = (bf16*)ws;    ws += 2 * wB;     // [Wi;Wf] concat; later Wg | Wo*w_norm
  float* aggP = (float*)ws; ws += (size_t)4 * N_DIM * NCHUNK * sizeof(float);
  float* aggH = (float*)ws; ws += (size_t)4 * N_DIM * NCHUNK * sizeof(float);
  float* rbuf = (float*)ws; ws += (size_t)M_DIM * sizeof(float);
  if ((size_t)(ws - (char*)d_ws) > ws_size) return;  // detectable: absmax 5.625
  bf16* W1b = Wif;                             // Wg region (reuse)
  bf16* W2b = Wif + (size_t)N_DIM * K_DIM;     // Wo*w_norm region (reuse)

  k_cvt_x  <<<(M_DIM * (size_t)K_DIM) / (256 * 8), 256, 0, stream>>>(x, Xb);
  k_cvt_wif<<<((size_t)N_DIM * K_DIM) / (256 * 8), 256, 0, stream>>>(Wi, Wf, Wif);
  k_gemm_if<<<(M_DIM / 256) * (2 * N_DIM / 256), 512, 0, stream>>>(Xb, Wif, Ibuf, Fbuf);
  k_scan1  <<<(4 * (N_DIM / 4) * NCHUNK) / 256, 256, 0, stream>>>(Ibuf, Fbuf, aggP, aggH);
  k_scan2  <<<(4 * N_DIM) / 256, 256, 0, stream>>>(aggP, aggH);
  k_scan3  <<<(4 * (N_DIM / 4) * NCHUNK) / 256, 256, 0, stream>>>(Ibuf, Fbuf, aggP);
  k_cvt_g_wos<<<((size_t)N_DIM * K_DIM) / (256 * 8), 256, 0, stream>>>(Wg, Wo, wn, W1b, W2b);
  k_gemm_g <<<(M_DIM / 256) * (N_DIM / 256), 512, 0, stream>>>(Xb, W1b, Ibuf, Fbuf);
  k_rownorm<<<M_DIM, 256, 0, stream>>>(Fbuf, rbuf);
  k_gemm_o <<<(M_DIM / 256) * (N_DIM / 256), 512, 0, stream>>>(Fbuf, W2b, rbuf, out);
}